// Round 11
// baseline (289.782 us; speedup 1.0000x reference)
//
#include <hip/hip_runtime.h>
#include <math.h>

#define DIM   1024
#define NH    16
#define HD    64
#define BATCH 2
#define SEQ   2048
#define EPS   1e-6f

#define NX  (BATCH * SEQ * DIM)
#define NWQ (3 * DIM * DIM)
#define NWP (DIM * DIM)

typedef __attribute__((ext_vector_type(8))) short bf16x8;
typedef __attribute__((ext_vector_type(4))) float f32x4;

#define EXP2F(x) __builtin_amdgcn_exp2f(x)
#define LOG2E 1.4426950408889634f
#define SOFTMAX_SHIFT 12.0f   // |s_log2| <= 11.6 by LN bound; fixed shift is safe

__device__ __forceinline__ float bf2f(unsigned short u) {
  return __uint_as_float(((unsigned int)u) << 16);
}
__device__ __forceinline__ unsigned short f2bf(float f) {
  unsigned int u = __float_as_uint(f);
  unsigned int r = (u + 0x7FFFu + ((u >> 16) & 1u)) >> 16;  // RNE
  return (unsigned short)r;
}
__device__ __forceinline__ unsigned int pack_bf16_trunc(float p0, float p1) {
  return (__float_as_uint(p1) & 0xFFFF0000u) | (__float_as_uint(p0) >> 16);
}

// async 16B/lane global->LDS DMA (attention staging only)
__device__ __forceinline__ void async_copy16(const void* g, void* l) {
  __builtin_amdgcn_global_load_lds(
      (const __attribute__((address_space(1))) unsigned int*)g,
      (__attribute__((address_space(3))) unsigned int*)l, 16, 0, 0);
}

// ---------------------------------------------------------------------------
// Dtype detector: flag=1 -> fp32 inputs, 0 -> bf16.
// ---------------------------------------------------------------------------
__global__ void detect_dtype(const unsigned short* __restrict__ w, int* __restrict__ flag) {
  __shared__ int cnt;
  if (threadIdx.x == 0) cnt = 0;
  __syncthreads();
  int c = 0;
  for (int i = threadIdx.x; i < 4096; i += 256) {
    unsigned short u = w[i];
    if ((u & 0x7F80u) >= 0x3F80u) ++c;
  }
  atomicAdd(&cnt, c);
  __syncthreads();
  if (threadIdx.x == 0) *flag = (cnt >= 64) ? 1 : 0;
}

// ---------------------------------------------------------------------------
// RoPE cos/sin table: tab[s*32+f] = (cos, sin)(s * 10000^{-f/32}).
// ---------------------------------------------------------------------------
__global__ __launch_bounds__(256)
void rope_table(float2* __restrict__ tab) {
  const int idx = blockIdx.x * 256 + threadIdx.x;
  const int s = idx >> 5, f = idx & 31;
  const float invf = expf(-((float)f * (1.f / 32.f)) * 9.210340371976184f);
  float sn, cs;
  sincosf((float)s * invf, &sn, &cs);
  tab[idx] = make_float2(cs, sn);
}

// ---------------------------------------------------------------------------
// Fused convert: x, w_qkv, w_proj -> bf16 in ONE launch.
// ---------------------------------------------------------------------------
__global__ __launch_bounds__(256)
void convert_all(const void* __restrict__ x, const void* __restrict__ wq,
                 const void* __restrict__ wp,
                 unsigned short* __restrict__ xb, unsigned short* __restrict__ wqb,
                 unsigned short* __restrict__ wpb, const int* __restrict__ flagp) {
  const bool isf32 = (*flagp != 0);
  int i = (blockIdx.x * 256 + threadIdx.x) * 8;
  const void* src;
  unsigned short* dst;
  if (i < NX) { src = x; dst = xb; }
  else if (i < NX + NWQ) { src = wq; dst = wqb; i -= NX; }
  else if (i < NX + NWQ + NWP) { src = wp; dst = wpb; i -= NX + NWQ; }
  else return;
  if (isf32) {
    const float* s = (const float*)src + i;
    float4 a = *(const float4*)s;
    float4 b = *(const float4*)(s + 4);
    ushort4 lo, hi;
    lo.x = f2bf(a.x); lo.y = f2bf(a.y); lo.z = f2bf(a.z); lo.w = f2bf(a.w);
    hi.x = f2bf(b.x); hi.y = f2bf(b.y); hi.z = f2bf(b.z); hi.w = f2bf(b.w);
    *(ushort4*)&dst[i] = lo;
    *(ushort4*)&dst[i + 4] = hi;
  } else {
    *(uint4*)&dst[i] = *(const uint4*)((const unsigned short*)src + i);
  }
}

__device__ __forceinline__ float ld_param(const void* p, bool isf32, int idx) {
  return isf32 ? ((const float*)p)[idx] : bf2f(((const unsigned short*)p)[idx]);
}

// ---------------------------------------------------------------------------
// QKV GEMM, REGISTER-DIRECT (no LDS, no barriers): each wave loads its MFMA
// fragments straight from global with immediate-offset dwordx4 off 8 base
// pointers; fully unrolled K with ping-pong frag regs -> compiler pipelines
// loads across MFMAs via fine vmcnt (AITER flatmm pattern). Fused LN/RoPE
// epilogue; V stored transposed; Q scaled 0.125*log2e.
// ---------------------------------------------------------------------------
__global__ __launch_bounds__(256)
void gemm_qkv(const unsigned short* __restrict__ A, const unsigned short* __restrict__ B,
              unsigned short* __restrict__ Qb, unsigned short* __restrict__ Kb,
              unsigned short* __restrict__ VbT,
              const void* __restrict__ qg, const void* __restrict__ qbe,
              const void* __restrict__ kg, const void* __restrict__ kbe,
              const float2* __restrict__ tab, const int* __restrict__ flagp) {
  const int K = DIM;
  const int tid  = threadIdx.x;
  const int wv   = tid >> 6;
  const int lane = tid & 63;
  const int l15  = lane & 15;
  const int quad = lane >> 4;
  const int wm = wv >> 1, wn = wv & 1;
  const int bm = blockIdx.y * 128;
  const int bn = blockIdx.x * 128;

  f32x4 acc[4][4];
#pragma unroll
  for (int i = 0; i < 4; ++i)
#pragma unroll
    for (int j = 0; j < 4; ++j) acc[i][j] = (f32x4){0.f, 0.f, 0.f, 0.f};

  // per-fragment base pointers (lane-resolved); all K-offsets are immediates
  const unsigned short* Ab[4];
  const unsigned short* Bb[4];
#pragma unroll
  for (int mt = 0; mt < 4; ++mt)
    Ab[mt] = A + (size_t)(bm + wm * 64 + mt * 16 + l15) * K + quad * 8;
#pragma unroll
  for (int nt = 0; nt < 4; ++nt)
    Bb[nt] = B + (size_t)(bn + wn * 64 + nt * 16 + l15) * K + quad * 8;

  bf16x8 a0[4], b0[4];
#pragma unroll
  for (int mt = 0; mt < 4; ++mt) a0[mt] = *(const bf16x8*)(Ab[mt]);
#pragma unroll
  for (int nt = 0; nt < 4; ++nt) b0[nt] = *(const bf16x8*)(Bb[nt]);

#pragma unroll
  for (int k0 = 0; k0 < DIM; k0 += 64) {
    bf16x8 a1[4], b1[4];
#pragma unroll
    for (int mt = 0; mt < 4; ++mt) a1[mt] = *(const bf16x8*)(Ab[mt] + k0 + 32);
#pragma unroll
    for (int nt = 0; nt < 4; ++nt) b1[nt] = *(const bf16x8*)(Bb[nt] + k0 + 32);
#pragma unroll
    for (int mt = 0; mt < 4; ++mt)
#pragma unroll
      for (int nt = 0; nt < 4; ++nt)
        acc[mt][nt] = __builtin_amdgcn_mfma_f32_16x16x32_bf16(a0[mt], b0[nt], acc[mt][nt], 0, 0, 0);
    if (k0 + 64 < DIM) {
#pragma unroll
      for (int mt = 0; mt < 4; ++mt) a0[mt] = *(const bf16x8*)(Ab[mt] + k0 + 64);
#pragma unroll
      for (int nt = 0; nt < 4; ++nt) b0[nt] = *(const bf16x8*)(Bb[nt] + k0 + 64);
    }
#pragma unroll
    for (int mt = 0; mt < 4; ++mt)
#pragma unroll
      for (int nt = 0; nt < 4; ++nt)
        acc[mt][nt] = __builtin_amdgcn_mfma_f32_16x16x32_bf16(a1[mt], b1[nt], acc[mt][nt], 0, 0, 0);
  }

  const bool isf32 = (*flagp != 0);
  const int type = bn >> 10;                 // 0=Q 1=K 2=V
  const int h = ((bn & 1023) >> 6) + wn;

  if (type == 2) {
    // store V transposed: VbT[(b*NH+h)*HD + d][s], 4 consecutive s per lane
#pragma unroll
    for (int mt = 0; mt < 4; ++mt) {
      const int r0 = bm + wm * 64 + mt * 16 + quad * 4;
      const int b = r0 >> 11, s0 = r0 & 2047;
#pragma unroll
      for (int nt = 0; nt < 4; ++nt) {
        const int d = nt * 16 + l15;
        uint2 pk;
        pk.x = ((unsigned int)f2bf(acc[mt][nt][1]) << 16) | f2bf(acc[mt][nt][0]);
        pk.y = ((unsigned int)f2bf(acc[mt][nt][3]) << 16) | f2bf(acc[mt][nt][2]);
        *(uint2*)&VbT[((size_t)(b * NH + h) * HD + d) * SEQ + s0] = pk;
      }
    }
    return;
  }

  unsigned short* plane = (type == 0) ? Qb : Kb;
  const void* gp = (type == 0) ? qg : kg;
  const void* bp = (type == 0) ? qbe : kbe;
  float gam[4], bet[4];
#pragma unroll
  for (int nt = 0; nt < 4; ++nt) {
    gam[nt] = ld_param(gp, isf32, nt * 16 + l15);
    bet[nt] = ld_param(bp, isf32, nt * 16 + l15);
  }
  const float scale = (type == 0) ? (0.125f * LOG2E) : 1.f;

#pragma unroll
  for (int mt = 0; mt < 4; ++mt)
#pragma unroll
    for (int rr = 0; rr < 4; ++rr) {
      const int r = bm + wm * 64 + mt * 16 + quad * 4 + rr;
      const int b = r >> 11, s = r & 2047;
      float sum = acc[mt][0][rr] + acc[mt][1][rr] + acc[mt][2][rr] + acc[mt][3][rr];
      sum += __shfl_xor(sum, 1); sum += __shfl_xor(sum, 2);
      sum += __shfl_xor(sum, 4); sum += __shfl_xor(sum, 8);
      const float mu = sum * (1.f / 64.f);
      float vs = 0.f;
#pragma unroll
      for (int nt = 0; nt < 4; ++nt) {
        const float d = acc[mt][nt][rr] - mu;
        vs += d * d;
      }
      vs += __shfl_xor(vs, 1); vs += __shfl_xor(vs, 2);
      vs += __shfl_xor(vs, 4); vs += __shfl_xor(vs, 8);
      const float rs = rsqrtf(vs * (1.f / 64.f) + EPS);
      float xn[4];
#pragma unroll
      for (int nt = 0; nt < 4; ++nt)
        xn[nt] = (acc[mt][nt][rr] - mu) * rs * gam[nt] + bet[nt];
      const float2 t0 = tab[s * 32 + l15];
      const float2 t1 = tab[s * 32 + 16 + l15];
      float ro[4];
      ro[0] = xn[0] * t0.x - xn[2] * t0.y;
      ro[2] = xn[2] * t0.x + xn[0] * t0.y;
      ro[1] = xn[1] * t1.x - xn[3] * t1.y;
      ro[3] = xn[3] * t1.x + xn[1] * t1.y;
      unsigned short* row = plane + (((size_t)(b * NH + h) * SEQ + s) * HD);
#pragma unroll
      for (int nt = 0; nt < 4; ++nt)
        row[nt * 16 + l15] = f2bf(ro[nt] * scale);
    }
}

// ---------------------------------------------------------------------------
// Flash attention (round-9/10 passing version, unchanged).
// ---------------------------------------------------------------------------
#define KIDX(g,k0,key,dim) (((((g)*2+(k0))*64+(key))*32)+(dim))
#define VOFF 8192
#define POFF 16384
#define PIDX(w,row,col) (POFF + ((w)*32+(row))*72 + (col))

__global__ __launch_bounds__(512, 4)
void attn_mfma5(const unsigned short* __restrict__ Qb, const unsigned short* __restrict__ Kb,
                const unsigned short* __restrict__ VbT, unsigned short* __restrict__ O) {
  __shared__ __attribute__((aligned(16))) unsigned short SMEM[34816];  // 68 KB

  const int tid  = threadIdx.x;
  const int wv   = tid >> 6;
  const int g    = wv >> 2;
  const int qsub = wv & 3;
  const int lane = tid & 63;
  const int l15  = lane & 15;
  const int quad = lane >> 4;
  const int bh = blockIdx.y;
  const int q0 = blockIdx.x * 128;
  const size_t base  = (size_t)bh * (SEQ * HD);
  const size_t baseT = (size_t)bh * (HD * SEQ);
  const int qsw = (quad ^ ((l15 >> 1) & 3)) * 8;

  bf16x8 qf[2][2];
#pragma unroll
  for (int mt = 0; mt < 2; ++mt)
#pragma unroll
    for (int k0 = 0; k0 < 2; ++k0)
      qf[mt][k0] = *(const bf16x8*)&Qb[base + (size_t)(q0 + qsub * 32 + mt * 16 + l15) * HD + k0 * 32 + quad * 8];

  bf16x8 ones;
#pragma unroll
  for (int j = 0; j < 8; ++j) ones[j] = (short)0x3F80;

  f32x4 oaccT[4][2];
  f32x4 ol[2];
#pragma unroll
  for (int nb = 0; nb < 4; ++nb)
#pragma unroll
    for (int mt = 0; mt < 2; ++mt) oaccT[nb][mt] = (f32x4){0.f, 0.f, 0.f, 0.f};
  ol[0] = (f32x4){0.f, 0.f, 0.f, 0.f};
  ol[1] = (f32x4){0.f, 0.f, 0.f, 0.f};

  const int sseg = (((lane & 3) ^ ((lane >> 3) & 3))) * 8;
  const unsigned short* srcK = Kb + base + (size_t)(qsub * 16 + (lane >> 2)) * HD + sseg;
  const unsigned short* srcV = VbT + baseT + (size_t)(qsub * 16 + (lane >> 2)) * SEQ + sseg;
  unsigned short* dstK0 = &SMEM[KIDX(g, 0, qsub * 16, 0)];
  unsigned short* dstK1 = &SMEM[KIDX(g, 1, qsub * 16, 0)];
  unsigned short* dstV0 = &SMEM[VOFF + KIDX(g, 0, qsub * 16, 0)];
  unsigned short* dstV1 = &SMEM[VOFF + KIDX(g, 1, qsub * 16, 0)];

  for (int it = 0; it < SEQ / 128; ++it) {
    const int kt = it * 128 + g * 64;
    __syncthreads();
    async_copy16(srcK + (size_t)kt * HD,      dstK0);
    async_copy16(srcK + (size_t)kt * HD + 32, dstK1);
    async_copy16(srcV + kt,                   dstV0);
    async_copy16(srcV + kt + 32,              dstV1);
    __syncthreads();

    f32x4 st[4][2];
#pragma unroll
    for (int nb = 0; nb < 4; ++nb)
#pragma unroll
      for (int mt = 0; mt < 2; ++mt) st[nb][mt] = (f32x4){0.f, 0.f, 0.f, 0.f};
#pragma unroll
    for (int k0 = 0; k0 < 2; ++k0)
#pragma unroll
      for (int nb = 0; nb < 4; ++nb) {
        bf16x8 kf = *(const bf16x8*)&SMEM[KIDX(g, k0, nb * 16 + l15, qsw)];
#pragma unroll
        for (int mt = 0; mt < 2; ++mt)
          st[nb][mt] = __builtin_amdgcn_mfma_f32_16x16x32_bf16(kf, qf[mt][k0], st[nb][mt], 0, 0, 0);
      }

#pragma unroll
    for (int mt = 0; mt < 2; ++mt)
#pragma unroll
      for (int nb = 0; nb < 4; ++nb) {
        const float p0 = EXP2F(st[nb][mt][0] - SOFTMAX_SHIFT);
        const float p1 = EXP2F(st[nb][mt][1] - SOFTMAX_SHIFT);
        const float p2 = EXP2F(st[nb][mt][2] - SOFTMAX_SHIFT);
        const float p3 = EXP2F(st[nb][mt][3] - SOFTMAX_SHIFT);
        uint2 pk;
        pk.x = pack_bf16_trunc(p0, p1);
        pk.y = pack_bf16_trunc(p2, p3);
        *(uint2*)&SMEM[PIDX(wv, mt * 16 + l15, nb * 16 + quad * 4)] = pk;
      }

#pragma unroll
    for (int k0 = 0; k0 < 2; ++k0) {
      bf16x8 pf0 = *(const bf16x8*)&SMEM[PIDX(wv, 0 * 16 + l15, k0 * 32 + quad * 8)];
      bf16x8 pf1 = *(const bf16x8*)&SMEM[PIDX(wv, 1 * 16 + l15, k0 * 32 + quad * 8)];
      ol[0] = __builtin_amdgcn_mfma_f32_16x16x32_bf16(ones, pf0, ol[0], 0, 0, 0);
      ol[1] = __builtin_amdgcn_mfma_f32_16x16x32_bf16(ones, pf1, ol[1], 0, 0, 0);
#pragma unroll
      for (int nb = 0; nb < 4; ++nb) {
        bf16x8 vf = *(const bf16x8*)&SMEM[VOFF + KIDX(g, k0, nb * 16 + l15, qsw)];
        oaccT[nb][0] = __builtin_amdgcn_mfma_f32_16x16x32_bf16(vf, pf0, oaccT[nb][0], 0, 0, 0);
        oaccT[nb][1] = __builtin_amdgcn_mfma_f32_16x16x32_bf16(vf, pf1, oaccT[nb][1], 0, 0, 0);
      }
    }
  }

  __syncthreads();
  f32x4* MO = (f32x4*)SMEM;
  float* ML = (float*)(SMEM + POFF);
  if (g == 1) {
#pragma unroll
    for (int mt = 0; mt < 2; ++mt) {
#pragma unroll
      for (int nb = 0; nb < 4; ++nb)
        MO[(((qsub * 2 + mt) * 4 + nb) << 6) + lane] = oaccT[nb][mt];
      if (quad == 0)
        ML[(qsub * 2 + mt) * 16 + l15] = ol[mt][0];
    }
  }
  __syncthreads();
  if (g == 0) {
    const int b = bh >> 4, h = bh & 15;
#pragma unroll
    for (int mt = 0; mt < 2; ++mt) {
      const float l1 = ML[(qsub * 2 + mt) * 16 + l15];
      const float inv = 1.f / (ol[mt][0] + l1);
      const int qrow = q0 + qsub * 32 + mt * 16 + l15;
      unsigned short* orow = O + ((size_t)(b * SEQ + qrow)) * DIM + h * HD;
#pragma unroll
      for (int nb = 0; nb < 4; ++nb) {
        f32x4 o1 = MO[(((qsub * 2 + mt) * 4 + nb) << 6) + lane];
        uint2 pk;
        pk.x = ((unsigned int)f2bf((oaccT[nb][mt][1] + o1[1]) * inv) << 16) |
               f2bf((oaccT[nb][mt][0] + o1[0]) * inv);
        pk.y = ((unsigned int)f2bf((oaccT[nb][mt][3] + o1[3]) * inv) << 16) |
               f2bf((oaccT[nb][mt][2] + o1[2]) * inv);
        *(uint2*)&orow[nb * 16 + quad * 4] = pk;
      }
    }
  }
}

// ---------------------------------------------------------------------------
// Output projection, REGISTER-DIRECT (no LDS/barriers), 128x64 tiles.
// ---------------------------------------------------------------------------
__global__ __launch_bounds__(256)
void gemm_out(const unsigned short* __restrict__ A, const unsigned short* __restrict__ B,
              const void* __restrict__ biasv, void* __restrict__ Cv,
              int M, int N, int K, const int* __restrict__ flagp) {
  const int tid  = threadIdx.x;
  const int wv   = tid >> 6;
  const int lane = tid & 63;
  const int l15  = lane & 15;
  const int quad = lane >> 4;
  const int wm = wv >> 1, wn = wv & 1;
  const int bm = blockIdx.y * 128;
  const int bn = blockIdx.x * 64;

  f32x4 acc[4][2];
#pragma unroll
  for (int i = 0; i < 4; ++i)
#pragma unroll
    for (int j = 0; j < 2; ++j) acc[i][j] = (f32x4){0.f, 0.f, 0.f, 0.f};

  const unsigned short* Ab[4];
  const unsigned short* Bb[2];
#pragma unroll
  for (int mt = 0; mt < 4; ++mt)
    Ab[mt] = A + (size_t)(bm + wm * 64 + mt * 16 + l15) * K + quad * 8;
#pragma unroll
  for (int nt = 0; nt < 2; ++nt)
    Bb[nt] = B + (size_t)(bn + wn * 32 + nt * 16 + l15) * K + quad * 8;

  bf16x8 a0[4], b0[2];
#pragma unroll
  for (int mt = 0; mt < 4; ++mt) a0[mt] = *(const bf16x8*)(Ab[mt]);
#pragma unroll
  for (int nt = 0; nt < 2; ++nt) b0[nt] = *(const bf16x8*)(Bb[nt]);

#pragma unroll
  for (int k0 = 0; k0 < DIM; k0 += 64) {
    bf16x8 a1[4], b1[2];
#pragma unroll
    for (int mt = 0; mt < 4; ++mt) a1[mt] = *(const bf16x8*)(Ab[mt] + k0 + 32);
#pragma unroll
    for (int nt = 0; nt < 2; ++nt) b1[nt] = *(const bf16x8*)(Bb[nt] + k0 + 32);
#pragma unroll
    for (int mt = 0; mt < 4; ++mt)
#pragma unroll
      for (int nt = 0; nt < 2; ++nt)
        acc[mt][nt] = __builtin_amdgcn_mfma_f32_16x16x32_bf16(a0[mt], b0[nt], acc[mt][nt], 0, 0, 0);
    if (k0 + 64 < DIM) {
#pragma unroll
      for (int mt = 0; mt < 4; ++mt) a0[mt] = *(const bf16x8*)(Ab[mt] + k0 + 64);
#pragma unroll
      for (int nt = 0; nt < 2; ++nt) b0[nt] = *(const bf16x8*)(Bb[nt] + k0 + 64);
    }
#pragma unroll
    for (int mt = 0; mt < 4; ++mt)
#pragma unroll
      for (int nt = 0; nt < 2; ++nt)
        acc[mt][nt] = __builtin_amdgcn_mfma_f32_16x16x32_bf16(a1[mt], b1[nt], acc[mt][nt], 0, 0, 0);
  }

  const bool isf32 = (*flagp != 0);
#pragma unroll
  for (int mt = 0; mt < 4; ++mt)
#pragma unroll
    for (int rr = 0; rr < 4; ++rr) {
      const int r = bm + wm * 64 + mt * 16 + quad * 4 + rr;
#pragma unroll
      for (int nt = 0; nt < 2; ++nt) {
        const int c = bn + wn * 32 + nt * 16 + l15;
        const float bias_c = isf32 ? ((const float*)biasv)[c]
                                   : bf2f(((const unsigned short*)biasv)[c]);
        const float o = acc[mt][nt][rr] + bias_c;
        if (isf32) ((float*)Cv)[(size_t)r * N + c] = o;
        else       ((unsigned short*)Cv)[(size_t)r * N + c] = f2bf(o);
      }
    }
}

// ---------------------------------------------------------------------------
extern "C" void kernel_launch(void* const* d_in, const int* in_sizes, int n_in,
                              void* d_out, int out_size, void* d_ws, size_t ws_size,
                              hipStream_t stream) {
  const void* x      = d_in[0];
  const void* w_qkv  = d_in[1];
  const void* w_proj = d_in[2];
  const void* b_proj = d_in[3];
  const void* q_g    = d_in[4];
  const void* q_b    = d_in[5];
  const void* k_g    = d_in[6];
  const void* k_b    = d_in[7];

  const size_t PLANE = (size_t)BATCH * NH * SEQ * HD;

  unsigned short* Qb  = (unsigned short*)d_ws;
  unsigned short* Kb  = Qb + PLANE;
  unsigned short* VbT = Kb + PLANE;
  unsigned short* xb  = VbT + PLANE;             // xb, later attnout
  unsigned short* wqb = xb + PLANE;
  unsigned short* wpb = wqb + NWQ;
  float2* tab = (float2*)(wpb + NWP);
  int* flag = (int*)(tab + SEQ * 32);

  hipLaunchKernelGGL(detect_dtype, dim3(1), dim3(256), 0, stream,
                     (const unsigned short*)w_qkv, flag);
  hipLaunchKernelGGL(rope_table, dim3(SEQ * 32 / 256), dim3(256), 0, stream, tab);
  hipLaunchKernelGGL(convert_all, dim3((NX + NWQ + NWP) / 8 / 256), dim3(256), 0, stream,
                     x, w_qkv, w_proj, xb, wqb, wpb, flag);

  {
    dim3 grid((3 * DIM) / 128, (BATCH * SEQ) / 128);
    hipLaunchKernelGGL(gemm_qkv, grid, dim3(256), 0, stream,
                       xb, wqb, Qb, Kb, VbT, q_g, q_b, k_g, k_b, tab, flag);
  }
  {
    dim3 grid(SEQ / 128, BATCH * NH);
    hipLaunchKernelGGL(attn_mfma5, grid, dim3(512), 0, stream,
                       Qb, Kb, VbT, xb);
  }
  {
    dim3 grid(DIM / 64, (BATCH * SEQ) / 128);
    hipLaunchKernelGGL(gemm_out, grid, dim3(256), 0, stream,
                       xb, wpb, b_proj, d_out, BATCH * SEQ, DIM, DIM, flag);
  }
}

// Round 12
// 199.932 us; speedup vs baseline: 1.4494x; 1.4494x over previous
//
#include <hip/hip_runtime.h>
#include <math.h>

#define DIM   1024
#define NH    16
#define HD    64
#define BATCH 2
#define SEQ   2048
#define EPS   1e-6f

#define NX  (BATCH * SEQ * DIM)
#define NWQ (3 * DIM * DIM)
#define NWP (DIM * DIM)

typedef __attribute__((ext_vector_type(8))) short bf16x8;
typedef __attribute__((ext_vector_type(4))) float f32x4;

#define EXP2F(x) __builtin_amdgcn_exp2f(x)
#define LOG2E 1.4426950408889634f
#define SOFTMAX_SHIFT 12.0f   // |s_log2| <= 11.6 by LN bound; fixed shift is safe

__device__ __forceinline__ float bf2f(unsigned short u) {
  return __uint_as_float(((unsigned int)u) << 16);
}
__device__ __forceinline__ unsigned short f2bf(float f) {
  unsigned int u = __float_as_uint(f);
  unsigned int r = (u + 0x7FFFu + ((u >> 16) & 1u)) >> 16;  // RNE
  return (unsigned short)r;
}
__device__ __forceinline__ unsigned int pack_bf16_trunc(float p0, float p1) {
  return (__float_as_uint(p1) & 0xFFFF0000u) | (__float_as_uint(p0) >> 16);
}

// async 16B/lane global->LDS DMA (m97 path)
__device__ __forceinline__ void async_copy16(const void* g, void* l) {
  __builtin_amdgcn_global_load_lds(
      (const __attribute__((address_space(1))) unsigned int*)g,
      (__attribute__((address_space(3))) unsigned int*)l, 16, 0, 0);
}

// XOR-swizzle (round-9 verified, conflicts=0): DMA src chunk for lane L is
// (L&3)^((L>>3)&3); frag read col = (quad^((l15>>1)&3))*8.

// ---------------------------------------------------------------------------
// Dtype detector: flag=1 -> fp32 inputs, 0 -> bf16.
// ---------------------------------------------------------------------------
__global__ void detect_dtype(const unsigned short* __restrict__ w, int* __restrict__ flag) {
  __shared__ int cnt;
  if (threadIdx.x == 0) cnt = 0;
  __syncthreads();
  int c = 0;
  for (int i = threadIdx.x; i < 4096; i += 256) {
    unsigned short u = w[i];
    if ((u & 0x7F80u) >= 0x3F80u) ++c;
  }
  atomicAdd(&cnt, c);
  __syncthreads();
  if (threadIdx.x == 0) *flag = (cnt >= 64) ? 1 : 0;
}

// ---------------------------------------------------------------------------
// RoPE cos/sin table: tab[s*32+f] = (cos, sin)(s * 10000^{-f/32}).
// ---------------------------------------------------------------------------
__global__ __launch_bounds__(256)
void rope_table(float2* __restrict__ tab) {
  const int idx = blockIdx.x * 256 + threadIdx.x;
  const int s = idx >> 5, f = idx & 31;
  const float invf = expf(-((float)f * (1.f / 32.f)) * 9.210340371976184f);
  float sn, cs;
  sincosf((float)s * invf, &sn, &cs);
  tab[idx] = make_float2(cs, sn);
}

// ---------------------------------------------------------------------------
// Fused convert: x, w_qkv, w_proj -> bf16 in ONE launch.
// ---------------------------------------------------------------------------
__global__ __launch_bounds__(256)
void convert_all(const void* __restrict__ x, const void* __restrict__ wq,
                 const void* __restrict__ wp,
                 unsigned short* __restrict__ xb, unsigned short* __restrict__ wqb,
                 unsigned short* __restrict__ wpb, const int* __restrict__ flagp) {
  const bool isf32 = (*flagp != 0);
  int i = (blockIdx.x * 256 + threadIdx.x) * 8;
  const void* src;
  unsigned short* dst;
  if (i < NX) { src = x; dst = xb; }
  else if (i < NX + NWQ) { src = wq; dst = wqb; i -= NX; }
  else if (i < NX + NWQ + NWP) { src = wp; dst = wpb; i -= NX + NWQ; }
  else return;
  if (isf32) {
    const float* s = (const float*)src + i;
    float4 a = *(const float4*)s;
    float4 b = *(const float4*)(s + 4);
    ushort4 lo, hi;
    lo.x = f2bf(a.x); lo.y = f2bf(a.y); lo.z = f2bf(a.z); lo.w = f2bf(a.w);
    hi.x = f2bf(b.x); hi.y = f2bf(b.y); hi.z = f2bf(b.z); hi.w = f2bf(b.w);
    *(ushort4*)&dst[i] = lo;
    *(ushort4*)&dst[i + 4] = hi;
  } else {
    *(uint4*)&dst[i] = *(const uint4*)((const unsigned short*)src + i);
  }
}

__device__ __forceinline__ float ld_param(const void* p, bool isf32, int idx) {
  return isf32 ? ((const float*)p)[idx] : bf2f(((const unsigned short*)p)[idx]);
}

// ---------------------------------------------------------------------------
// QKV GEMM + fused LN/RoPE epilogue. 512 threads = 8 waves on the 128x128
// tile (wave = 32 rows x 64 cols = one head): same per-wave hot-loop density,
// 2x waves/CU (24) to hide the barrier drain (R8 split trick applied to GEMM).
// Double-buffered swizzled global_load_lds (one A + one B async per thread
// per iter). V stored transposed; Q scaled 0.125*log2e.
// ---------------------------------------------------------------------------
__global__ __launch_bounds__(512)
void gemm_qkv(const unsigned short* __restrict__ A, const unsigned short* __restrict__ B,
              unsigned short* __restrict__ Qb, unsigned short* __restrict__ Kb,
              unsigned short* __restrict__ VbT,
              const void* __restrict__ qg, const void* __restrict__ qbe,
              const void* __restrict__ kg, const void* __restrict__ kbe,
              const float2* __restrict__ tab, const int* __restrict__ flagp) {
  __shared__ __attribute__((aligned(16))) unsigned short As[2][128 * 32];  // 16 KB
  __shared__ __attribute__((aligned(16))) unsigned short Bs[2][128 * 32];  // 16 KB

  const int K = DIM;
  const int tid  = threadIdx.x;
  const int wv   = tid >> 6;        // 0..7
  const int lane = tid & 63;
  const int l15  = lane & 15;
  const int quad = lane >> 4;
  const int wm = wv & 3;            // row group (32 rows)
  const int wn = wv >> 2;           // col group (64 cols = one head)
  const int bm = blockIdx.y * 128;
  const int bn = blockIdx.x * 128;
  const int qsw = (quad ^ ((l15 >> 1) & 3)) * 8;  // swizzled read col

  f32x4 acc[2][4];
#pragma unroll
  for (int i = 0; i < 2; ++i)
#pragma unroll
    for (int j = 0; j < 4; ++j) acc[i][j] = (f32x4){0.f, 0.f, 0.f, 0.f};

  // staging: 512 threads cover the full 128x32 tile in ONE async per matrix
  const int srow = tid >> 2;                              // 0..127
  const int kseg = (((tid & 3) ^ ((tid >> 3) & 3))) * 8;  // swizzled DMA src
  const unsigned short* Ag = A + (size_t)(bm + srow) * K + kseg;
  const unsigned short* Bg = B + (size_t)(bn + srow) * K + kseg;

  // preload tile 0 -> buffer 0 (wave-uniform dest = wv*512 shorts)
  async_copy16(Ag, &As[0][wv * 512]);
  async_copy16(Bg, &Bs[0][wv * 512]);
  __syncthreads();

  for (int k0 = 0; k0 < K; k0 += 32) {
    const int cur = (k0 >> 5) & 1, nxt = cur ^ 1;
    if (k0 + 32 < K) {
      async_copy16(Ag + k0 + 32, &As[nxt][wv * 512]);
      async_copy16(Bg + k0 + 32, &Bs[nxt][wv * 512]);
    }

    bf16x8 af[2], bf[4];
#pragma unroll
    for (int mt = 0; mt < 2; ++mt)
      af[mt] = *(const bf16x8*)&As[cur][(wm * 32 + mt * 16 + l15) * 32 + qsw];
#pragma unroll
    for (int nt = 0; nt < 4; ++nt)
      bf[nt] = *(const bf16x8*)&Bs[cur][(wn * 64 + nt * 16 + l15) * 32 + qsw];
#pragma unroll
    for (int mt = 0; mt < 2; ++mt)
#pragma unroll
      for (int nt = 0; nt < 4; ++nt)
        acc[mt][nt] = __builtin_amdgcn_mfma_f32_16x16x32_bf16(af[mt], bf[nt], acc[mt][nt], 0, 0, 0);
    __syncthreads();
  }

  const bool isf32 = (*flagp != 0);
  const int type = bn >> 10;                 // 0=Q 1=K 2=V
  const int h = ((bn & 1023) >> 6) + wn;

  if (type == 2) {
    // store V transposed: VbT[(b*NH+h)*HD + d][s], 4 consecutive s per lane
#pragma unroll
    for (int mt = 0; mt < 2; ++mt) {
      const int r0 = bm + wm * 32 + mt * 16 + quad * 4;
      const int b = r0 >> 11, s0 = r0 & 2047;
#pragma unroll
      for (int nt = 0; nt < 4; ++nt) {
        const int d = nt * 16 + l15;
        uint2 pk;
        pk.x = ((unsigned int)f2bf(acc[mt][nt][1]) << 16) | f2bf(acc[mt][nt][0]);
        pk.y = ((unsigned int)f2bf(acc[mt][nt][3]) << 16) | f2bf(acc[mt][nt][2]);
        *(uint2*)&VbT[((size_t)(b * NH + h) * HD + d) * SEQ + s0] = pk;
      }
    }
    return;
  }

  unsigned short* plane = (type == 0) ? Qb : Kb;
  const void* gp = (type == 0) ? qg : kg;
  const void* bp = (type == 0) ? qbe : kbe;
  float gam[4], bet[4];
#pragma unroll
  for (int nt = 0; nt < 4; ++nt) {
    gam[nt] = ld_param(gp, isf32, nt * 16 + l15);
    bet[nt] = ld_param(bp, isf32, nt * 16 + l15);
  }
  const float scale = (type == 0) ? (0.125f * LOG2E) : 1.f;

#pragma unroll
  for (int mt = 0; mt < 2; ++mt)
#pragma unroll
    for (int rr = 0; rr < 4; ++rr) {
      const int r = bm + wm * 32 + mt * 16 + quad * 4 + rr;
      const int b = r >> 11, s = r & 2047;
      float sum = acc[mt][0][rr] + acc[mt][1][rr] + acc[mt][2][rr] + acc[mt][3][rr];
      sum += __shfl_xor(sum, 1); sum += __shfl_xor(sum, 2);
      sum += __shfl_xor(sum, 4); sum += __shfl_xor(sum, 8);
      const float mu = sum * (1.f / 64.f);
      float vs = 0.f;
#pragma unroll
      for (int nt = 0; nt < 4; ++nt) {
        const float d = acc[mt][nt][rr] - mu;
        vs += d * d;
      }
      vs += __shfl_xor(vs, 1); vs += __shfl_xor(vs, 2);
      vs += __shfl_xor(vs, 4); vs += __shfl_xor(vs, 8);
      const float rs = rsqrtf(vs * (1.f / 64.f) + EPS);
      float xn[4];
#pragma unroll
      for (int nt = 0; nt < 4; ++nt)
        xn[nt] = (acc[mt][nt][rr] - mu) * rs * gam[nt] + bet[nt];
      const float2 t0 = tab[s * 32 + l15];
      const float2 t1 = tab[s * 32 + 16 + l15];
      float ro[4];
      ro[0] = xn[0] * t0.x - xn[2] * t0.y;
      ro[2] = xn[2] * t0.x + xn[0] * t0.y;
      ro[1] = xn[1] * t1.x - xn[3] * t1.y;
      ro[3] = xn[3] * t1.x + xn[1] * t1.y;
      unsigned short* row = plane + (((size_t)(b * NH + h) * SEQ + s) * HD);
#pragma unroll
      for (int nt = 0; nt < 4; ++nt)
        row[nt * 16 + l15] = f2bf(ro[nt] * scale);
    }
}

// ---------------------------------------------------------------------------
// Flash attention (round-9/10 passing version, unchanged).
// ---------------------------------------------------------------------------
#define KIDX(g,k0,key,dim) (((((g)*2+(k0))*64+(key))*32)+(dim))
#define VOFF 8192
#define POFF 16384
#define PIDX(w,row,col) (POFF + ((w)*32+(row))*72 + (col))

__global__ __launch_bounds__(512, 4)
void attn_mfma5(const unsigned short* __restrict__ Qb, const unsigned short* __restrict__ Kb,
                const unsigned short* __restrict__ VbT, unsigned short* __restrict__ O) {
  __shared__ __attribute__((aligned(16))) unsigned short SMEM[34816];  // 68 KB

  const int tid  = threadIdx.x;
  const int wv   = tid >> 6;
  const int g    = wv >> 2;
  const int qsub = wv & 3;
  const int lane = tid & 63;
  const int l15  = lane & 15;
  const int quad = lane >> 4;
  const int bh = blockIdx.y;
  const int q0 = blockIdx.x * 128;
  const size_t base  = (size_t)bh * (SEQ * HD);
  const size_t baseT = (size_t)bh * (HD * SEQ);
  const int qsw = (quad ^ ((l15 >> 1) & 3)) * 8;

  bf16x8 qf[2][2];
#pragma unroll
  for (int mt = 0; mt < 2; ++mt)
#pragma unroll
    for (int k0 = 0; k0 < 2; ++k0)
      qf[mt][k0] = *(const bf16x8*)&Qb[base + (size_t)(q0 + qsub * 32 + mt * 16 + l15) * HD + k0 * 32 + quad * 8];

  bf16x8 ones;
#pragma unroll
  for (int j = 0; j < 8; ++j) ones[j] = (short)0x3F80;

  f32x4 oaccT[4][2];
  f32x4 ol[2];
#pragma unroll
  for (int nb = 0; nb < 4; ++nb)
#pragma unroll
    for (int mt = 0; mt < 2; ++mt) oaccT[nb][mt] = (f32x4){0.f, 0.f, 0.f, 0.f};
  ol[0] = (f32x4){0.f, 0.f, 0.f, 0.f};
  ol[1] = (f32x4){0.f, 0.f, 0.f, 0.f};

  const int sseg = (((lane & 3) ^ ((lane >> 3) & 3))) * 8;
  const unsigned short* srcK = Kb + base + (size_t)(qsub * 16 + (lane >> 2)) * HD + sseg;
  const unsigned short* srcV = VbT + baseT + (size_t)(qsub * 16 + (lane >> 2)) * SEQ + sseg;
  unsigned short* dstK0 = &SMEM[KIDX(g, 0, qsub * 16, 0)];
  unsigned short* dstK1 = &SMEM[KIDX(g, 1, qsub * 16, 0)];
  unsigned short* dstV0 = &SMEM[VOFF + KIDX(g, 0, qsub * 16, 0)];
  unsigned short* dstV1 = &SMEM[VOFF + KIDX(g, 1, qsub * 16, 0)];

  for (int it = 0; it < SEQ / 128; ++it) {
    const int kt = it * 128 + g * 64;
    __syncthreads();
    async_copy16(srcK + (size_t)kt * HD,      dstK0);
    async_copy16(srcK + (size_t)kt * HD + 32, dstK1);
    async_copy16(srcV + kt,                   dstV0);
    async_copy16(srcV + kt + 32,              dstV1);
    __syncthreads();

    f32x4 st[4][2];
#pragma unroll
    for (int nb = 0; nb < 4; ++nb)
#pragma unroll
      for (int mt = 0; mt < 2; ++mt) st[nb][mt] = (f32x4){0.f, 0.f, 0.f, 0.f};
#pragma unroll
    for (int k0 = 0; k0 < 2; ++k0)
#pragma unroll
      for (int nb = 0; nb < 4; ++nb) {
        bf16x8 kf = *(const bf16x8*)&SMEM[KIDX(g, k0, nb * 16 + l15, qsw)];
#pragma unroll
        for (int mt = 0; mt < 2; ++mt)
          st[nb][mt] = __builtin_amdgcn_mfma_f32_16x16x32_bf16(kf, qf[mt][k0], st[nb][mt], 0, 0, 0);
      }

#pragma unroll
    for (int mt = 0; mt < 2; ++mt)
#pragma unroll
      for (int nb = 0; nb < 4; ++nb) {
        const float p0 = EXP2F(st[nb][mt][0] - SOFTMAX_SHIFT);
        const float p1 = EXP2F(st[nb][mt][1] - SOFTMAX_SHIFT);
        const float p2 = EXP2F(st[nb][mt][2] - SOFTMAX_SHIFT);
        const float p3 = EXP2F(st[nb][mt][3] - SOFTMAX_SHIFT);
        uint2 pk;
        pk.x = pack_bf16_trunc(p0, p1);
        pk.y = pack_bf16_trunc(p2, p3);
        *(uint2*)&SMEM[PIDX(wv, mt * 16 + l15, nb * 16 + quad * 4)] = pk;
      }

#pragma unroll
    for (int k0 = 0; k0 < 2; ++k0) {
      bf16x8 pf0 = *(const bf16x8*)&SMEM[PIDX(wv, 0 * 16 + l15, k0 * 32 + quad * 8)];
      bf16x8 pf1 = *(const bf16x8*)&SMEM[PIDX(wv, 1 * 16 + l15, k0 * 32 + quad * 8)];
      ol[0] = __builtin_amdgcn_mfma_f32_16x16x32_bf16(ones, pf0, ol[0], 0, 0, 0);
      ol[1] = __builtin_amdgcn_mfma_f32_16x16x32_bf16(ones, pf1, ol[1], 0, 0, 0);
#pragma unroll
      for (int nb = 0; nb < 4; ++nb) {
        bf16x8 vf = *(const bf16x8*)&SMEM[VOFF + KIDX(g, k0, nb * 16 + l15, qsw)];
        oaccT[nb][0] = __builtin_amdgcn_mfma_f32_16x16x32_bf16(vf, pf0, oaccT[nb][0], 0, 0, 0);
        oaccT[nb][1] = __builtin_amdgcn_mfma_f32_16x16x32_bf16(vf, pf1, oaccT[nb][1], 0, 0, 0);
      }
    }
  }

  __syncthreads();
  f32x4* MO = (f32x4*)SMEM;
  float* ML = (float*)(SMEM + POFF);
  if (g == 1) {
#pragma unroll
    for (int mt = 0; mt < 2; ++mt) {
#pragma unroll
      for (int nb = 0; nb < 4; ++nb)
        MO[(((qsub * 2 + mt) * 4 + nb) << 6) + lane] = oaccT[nb][mt];
      if (quad == 0)
        ML[(qsub * 2 + mt) * 16 + l15] = ol[mt][0];
    }
  }
  __syncthreads();
  if (g == 0) {
    const int b = bh >> 4, h = bh & 15;
#pragma unroll
    for (int mt = 0; mt < 2; ++mt) {
      const float l1 = ML[(qsub * 2 + mt) * 16 + l15];
      const float inv = 1.f / (ol[mt][0] + l1);
      const int qrow = q0 + qsub * 32 + mt * 16 + l15;
      unsigned short* orow = O + ((size_t)(b * SEQ + qrow)) * DIM + h * HD;
#pragma unroll
      for (int nb = 0; nb < 4; ++nb) {
        f32x4 o1 = MO[(((qsub * 2 + mt) * 4 + nb) << 6) + lane];
        uint2 pk;
        pk.x = ((unsigned int)f2bf((oaccT[nb][mt][1] + o1[1]) * inv) << 16) |
               f2bf((oaccT[nb][mt][0] + o1[0]) * inv);
        pk.y = ((unsigned int)f2bf((oaccT[nb][mt][3] + o1[3]) * inv) << 16) |
               f2bf((oaccT[nb][mt][2] + o1[2]) * inv);
        *(uint2*)&orow[nb * 16 + quad * 4] = pk;
      }
    }
  }
}

// ---------------------------------------------------------------------------
// Output projection (round-10 proven LDS form): 128x64 tiles, double-buffered
// prefetch K-loop, swizzled staging.
// ---------------------------------------------------------------------------
__global__ __launch_bounds__(256)
void gemm_out(const unsigned short* __restrict__ A, const unsigned short* __restrict__ B,
              const void* __restrict__ biasv, void* __restrict__ Cv,
              int M, int N, int K, const int* __restrict__ flagp) {
  __shared__ __attribute__((aligned(16))) unsigned short As[2][128 * 32];  // 16 KB
  __shared__ __attribute__((aligned(16))) unsigned short Bs[2][64 * 32];   // 8 KB

  const int tid  = threadIdx.x;
  const int wv   = tid >> 6;
  const int lane = tid & 63;
  const int l15  = lane & 15;
  const int quad = lane >> 4;
  const int wm = wv >> 1, wn = wv & 1;
  const int bm = blockIdx.y * 128;
  const int bn = blockIdx.x * 64;
  const int qsw = (quad ^ ((l15 >> 1) & 3)) * 8;

  f32x4 acc[4][2];
#pragma unroll
  for (int i = 0; i < 4; ++i)
#pragma unroll
    for (int j = 0; j < 2; ++j) acc[i][j] = (f32x4){0.f, 0.f, 0.f, 0.f};

  const int srow = tid >> 2;
  const int kseg = (((tid & 3) ^ ((tid >> 3) & 3))) * 8;
  const unsigned short* Ag = A + (size_t)(bm + srow) * K + kseg;
  const unsigned short* Bg = B + (size_t)(bn + srow) * K + kseg;

  async_copy16(Ag, &As[0][wv * 512]);
  async_copy16(Ag + (size_t)64 * K, &As[0][wv * 512 + 2048]);
  async_copy16(Bg, &Bs[0][wv * 512]);
  __syncthreads();

  for (int k0 = 0; k0 < K; k0 += 32) {
    const int cur = (k0 >> 5) & 1, nxt = cur ^ 1;
    if (k0 + 32 < K) {
      async_copy16(Ag + k0 + 32, &As[nxt][wv * 512]);
      async_copy16(Ag + (size_t)64 * K + k0 + 32, &As[nxt][wv * 512 + 2048]);
      async_copy16(Bg + k0 + 32, &Bs[nxt][wv * 512]);
    }

    bf16x8 af[4], bf[2];
#pragma unroll
    for (int mt = 0; mt < 4; ++mt)
      af[mt] = *(const bf16x8*)&As[cur][(wm * 64 + mt * 16 + l15) * 32 + qsw];
#pragma unroll
    for (int nt = 0; nt < 2; ++nt)
      bf[nt] = *(const bf16x8*)&Bs[cur][(wn * 32 + nt * 16 + l15) * 32 + qsw];
#pragma unroll
    for (int mt = 0; mt < 4; ++mt)
#pragma unroll
      for (int nt = 0; nt < 2; ++nt)
        acc[mt][nt] = __builtin_amdgcn_mfma_f32_16x16x32_bf16(af[mt], bf[nt], acc[mt][nt], 0, 0, 0);
    __syncthreads();
  }

  const bool isf32 = (*flagp != 0);
#pragma unroll
  for (int mt = 0; mt < 4; ++mt)
#pragma unroll
    for (int rr = 0; rr < 4; ++rr) {
      const int r = bm + wm * 64 + mt * 16 + quad * 4 + rr;
#pragma unroll
      for (int nt = 0; nt < 2; ++nt) {
        const int c = bn + wn * 32 + nt * 16 + l15;
        const float bias_c = isf32 ? ((const float*)biasv)[c]
                                   : bf2f(((const unsigned short*)biasv)[c]);
        const float o = acc[mt][nt][rr] + bias_c;
        if (isf32) ((float*)Cv)[(size_t)r * N + c] = o;
        else       ((unsigned short*)Cv)[(size_t)r * N + c] = f2bf(o);
      }
    }
}

// ---------------------------------------------------------------------------
extern "C" void kernel_launch(void* const* d_in, const int* in_sizes, int n_in,
                              void* d_out, int out_size, void* d_ws, size_t ws_size,
                              hipStream_t stream) {
  const void* x      = d_in[0];
  const void* w_qkv  = d_in[1];
  const void* w_proj = d_in[2];
  const void* b_proj = d_in[3];
  const void* q_g    = d_in[4];
  const void* q_b    = d_in[5];
  const void* k_g    = d_in[6];
  const void* k_b    = d_in[7];

  const size_t PLANE = (size_t)BATCH * NH * SEQ * HD;

  unsigned short* Qb  = (unsigned short*)d_ws;
  unsigned short* Kb  = Qb + PLANE;
  unsigned short* VbT = Kb + PLANE;
  unsigned short* xb  = VbT + PLANE;             // xb, later attnout
  unsigned short* wqb = xb + PLANE;
  unsigned short* wpb = wqb + NWQ;
  float2* tab = (float2*)(wpb + NWP);
  int* flag = (int*)(tab + SEQ * 32);

  hipLaunchKernelGGL(detect_dtype, dim3(1), dim3(256), 0, stream,
                     (const unsigned short*)w_qkv, flag);
  hipLaunchKernelGGL(rope_table, dim3(SEQ * 32 / 256), dim3(256), 0, stream, tab);
  hipLaunchKernelGGL(convert_all, dim3((NX + NWQ + NWP) / 8 / 256), dim3(256), 0, stream,
                     x, w_qkv, w_proj, xb, wqb, wpb, flag);

  {
    dim3 grid((3 * DIM) / 128, (BATCH * SEQ) / 128);
    hipLaunchKernelGGL(gemm_qkv, grid, dim3(512), 0, stream,
                       xb, wqb, Qb, Kb, VbT, q_g, q_b, k_g, k_b, tab, flag);
  }
  {
    dim3 grid(SEQ / 128, BATCH * NH);
    hipLaunchKernelGGL(attn_mfma5, grid, dim3(512), 0, stream,
                       Qb, Kb, VbT, xb);
  }
  {
    dim3 grid(DIM / 64, (BATCH * SEQ) / 128);
    hipLaunchKernelGGL(gemm_out, grid, dim3(256), 0, stream,
                       xb, wpb, b_proj, d_out, BATCH * SEQ, DIM, DIM, flag);
  }
}

// Round 13
// 194.580 us; speedup vs baseline: 1.4893x; 1.0275x over previous
//
#include <hip/hip_runtime.h>
#include <math.h>

#define DIM   1024
#define NH    16
#define HD    64
#define BATCH 2
#define SEQ   2048
#define EPS   1e-6f

#define NX  (BATCH * SEQ * DIM)
#define NWQ (3 * DIM * DIM)
#define NWP (DIM * DIM)
#define NCONVBLK ((NX + NWQ + NWP) / 8 / 256)   // 4096
#define NTABBLK  (SEQ * 32 / 256)               // 256

typedef __attribute__((ext_vector_type(8))) short bf16x8;
typedef __attribute__((ext_vector_type(4))) float f32x4;

#define EXP2F(x) __builtin_amdgcn_exp2f(x)
#define LOG2E 1.4426950408889634f

__device__ __forceinline__ float bf2f(unsigned short u) {
  return __uint_as_float(((unsigned int)u) << 16);
}
__device__ __forceinline__ unsigned short f2bf(float f) {
  unsigned int u = __float_as_uint(f);
  unsigned int r = (u + 0x7FFFu + ((u >> 16) & 1u)) >> 16;  // RNE
  return (unsigned short)r;
}
// pack two fp32 -> two bf16 (truncation) in ONE v_perm_b32
__device__ __forceinline__ unsigned int pack_bf16_trunc(float p0, float p1) {
  return __builtin_amdgcn_perm(__float_as_uint(p1), __float_as_uint(p0), 0x07060302u);
}

// async 16B/lane global->LDS DMA (m97 path)
__device__ __forceinline__ void async_copy16(const void* g, void* l) {
  __builtin_amdgcn_global_load_lds(
      (const __attribute__((address_space(1))) unsigned int*)g,
      (__attribute__((address_space(3))) unsigned int*)l, 16, 0, 0);
}

// XOR-swizzle (round-9 verified, conflicts=0): DMA src chunk for lane L is
// (L&3)^((L>>3)&3); frag read col = (quad^((l15>>1)&3))*8.

// ---------------------------------------------------------------------------
// prep: fused dtype-detect + RoPE table + bf16 convert (one dispatch).
// Blocks [0,4096): convert x/w_qkv/w_proj (each block self-detects dtype from
// 256 u16 of w_qkv; ~128 hits if fp32-misread, 0 if bf16). Block 0 publishes
// the flag for downstream kernels. Blocks [4096,4352): RoPE cos/sin table.
// ---------------------------------------------------------------------------
__global__ __launch_bounds__(256)
void prep(const void* __restrict__ x, const void* __restrict__ wq,
          const void* __restrict__ wp,
          unsigned short* __restrict__ xb, unsigned short* __restrict__ wqb,
          unsigned short* __restrict__ wpb, float2* __restrict__ tab,
          int* __restrict__ flag) {
  const int bid = blockIdx.x, tid = threadIdx.x;

  if (bid >= NCONVBLK) {
    const int idx = (bid - NCONVBLK) * 256 + tid;  // [0, 65536)
    const int s = idx >> 5, f = idx & 31;
    const float invf = expf(-((float)f * (1.f / 32.f)) * 9.210340371976184f);
    float sn, cs;
    sincosf((float)s * invf, &sn, &cs);
    tab[idx] = make_float2(cs, sn);
    return;
  }

  // local dtype detect
  __shared__ int cnt;
  if (tid == 0) cnt = 0;
  __syncthreads();
  {
    unsigned short u = ((const unsigned short*)wq)[tid];
    if ((u & 0x7F80u) >= 0x3F80u) atomicAdd(&cnt, 1);
  }
  __syncthreads();
  const bool isf32 = (cnt >= 16);
  if (bid == 0 && tid == 0) *flag = isf32 ? 1 : 0;

  int i = (bid * 256 + tid) * 8;
  const void* src;
  unsigned short* dst;
  if (i < NX) { src = x; dst = xb; }
  else if (i < NX + NWQ) { src = wq; dst = wqb; i -= NX; }
  else { src = wp; dst = wpb; i -= NX + NWQ; }
  if (isf32) {
    const float* s = (const float*)src + i;
    float4 a = *(const float4*)s;
    float4 b = *(const float4*)(s + 4);
    ushort4 lo, hi;
    lo.x = f2bf(a.x); lo.y = f2bf(a.y); lo.z = f2bf(a.z); lo.w = f2bf(a.w);
    hi.x = f2bf(b.x); hi.y = f2bf(b.y); hi.z = f2bf(b.z); hi.w = f2bf(b.w);
    *(ushort4*)&dst[i] = lo;
    *(ushort4*)&dst[i + 4] = hi;
  } else {
    *(uint4*)&dst[i] = *(const uint4*)((const unsigned short*)src + i);
  }
}

__device__ __forceinline__ float ld_param(const void* p, bool isf32, int idx) {
  return isf32 ? ((const float*)p)[idx] : bf2f(((const unsigned short*)p)[idx]);
}

// ---------------------------------------------------------------------------
// QKV GEMM + fused LN/RoPE epilogue (round-12 passing version, unchanged):
// 512 thr = 8 waves on 128x128 tile (wave = 32 rows x 64 cols = one head),
// double-buffered swizzled global_load_lds. V stored transposed.
// Q scaled 0.125*log2e -> attention softmax in exp2 domain.
// ---------------------------------------------------------------------------
__global__ __launch_bounds__(512)
void gemm_qkv(const unsigned short* __restrict__ A, const unsigned short* __restrict__ B,
              unsigned short* __restrict__ Qb, unsigned short* __restrict__ Kb,
              unsigned short* __restrict__ VbT,
              const void* __restrict__ qg, const void* __restrict__ qbe,
              const void* __restrict__ kg, const void* __restrict__ kbe,
              const float2* __restrict__ tab, const int* __restrict__ flagp) {
  __shared__ __attribute__((aligned(16))) unsigned short As[2][128 * 32];
  __shared__ __attribute__((aligned(16))) unsigned short Bs[2][128 * 32];

  const int K = DIM;
  const int tid  = threadIdx.x;
  const int wv   = tid >> 6;
  const int lane = tid & 63;
  const int l15  = lane & 15;
  const int quad = lane >> 4;
  const int wm = wv & 3;
  const int wn = wv >> 2;
  const int bm = blockIdx.y * 128;
  const int bn = blockIdx.x * 128;
  const int qsw = (quad ^ ((l15 >> 1) & 3)) * 8;

  f32x4 acc[2][4];
#pragma unroll
  for (int i = 0; i < 2; ++i)
#pragma unroll
    for (int j = 0; j < 4; ++j) acc[i][j] = (f32x4){0.f, 0.f, 0.f, 0.f};

  const int srow = tid >> 2;
  const int kseg = (((tid & 3) ^ ((tid >> 3) & 3))) * 8;
  const unsigned short* Ag = A + (size_t)(bm + srow) * K + kseg;
  const unsigned short* Bg = B + (size_t)(bn + srow) * K + kseg;

  async_copy16(Ag, &As[0][wv * 512]);
  async_copy16(Bg, &Bs[0][wv * 512]);
  __syncthreads();

  for (int k0 = 0; k0 < K; k0 += 32) {
    const int cur = (k0 >> 5) & 1, nxt = cur ^ 1;
    if (k0 + 32 < K) {
      async_copy16(Ag + k0 + 32, &As[nxt][wv * 512]);
      async_copy16(Bg + k0 + 32, &Bs[nxt][wv * 512]);
    }

    bf16x8 af[2], bf[4];
#pragma unroll
    for (int mt = 0; mt < 2; ++mt)
      af[mt] = *(const bf16x8*)&As[cur][(wm * 32 + mt * 16 + l15) * 32 + qsw];
#pragma unroll
    for (int nt = 0; nt < 4; ++nt)
      bf[nt] = *(const bf16x8*)&Bs[cur][(wn * 64 + nt * 16 + l15) * 32 + qsw];
#pragma unroll
    for (int mt = 0; mt < 2; ++mt)
#pragma unroll
      for (int nt = 0; nt < 4; ++nt)
        acc[mt][nt] = __builtin_amdgcn_mfma_f32_16x16x32_bf16(af[mt], bf[nt], acc[mt][nt], 0, 0, 0);
    __syncthreads();
  }

  const bool isf32 = (*flagp != 0);
  const int type = bn >> 10;                 // 0=Q 1=K 2=V
  const int h = ((bn & 1023) >> 6) + wn;

  if (type == 2) {
#pragma unroll
    for (int mt = 0; mt < 2; ++mt) {
      const int r0 = bm + wm * 32 + mt * 16 + quad * 4;
      const int b = r0 >> 11, s0 = r0 & 2047;
#pragma unroll
      for (int nt = 0; nt < 4; ++nt) {
        const int d = nt * 16 + l15;
        uint2 pk;
        pk.x = ((unsigned int)f2bf(acc[mt][nt][1]) << 16) | f2bf(acc[mt][nt][0]);
        pk.y = ((unsigned int)f2bf(acc[mt][nt][3]) << 16) | f2bf(acc[mt][nt][2]);
        *(uint2*)&VbT[((size_t)(b * NH + h) * HD + d) * SEQ + s0] = pk;
      }
    }
    return;
  }

  unsigned short* plane = (type == 0) ? Qb : Kb;
  const void* gp = (type == 0) ? qg : kg;
  const void* bp = (type == 0) ? qbe : kbe;
  float gam[4], bet[4];
#pragma unroll
  for (int nt = 0; nt < 4; ++nt) {
    gam[nt] = ld_param(gp, isf32, nt * 16 + l15);
    bet[nt] = ld_param(bp, isf32, nt * 16 + l15);
  }
  const float scale = (type == 0) ? (0.125f * LOG2E) : 1.f;

#pragma unroll
  for (int mt = 0; mt < 2; ++mt)
#pragma unroll
    for (int rr = 0; rr < 4; ++rr) {
      const int r = bm + wm * 32 + mt * 16 + quad * 4 + rr;
      const int b = r >> 11, s = r & 2047;
      float sum = acc[mt][0][rr] + acc[mt][1][rr] + acc[mt][2][rr] + acc[mt][3][rr];
      sum += __shfl_xor(sum, 1); sum += __shfl_xor(sum, 2);
      sum += __shfl_xor(sum, 4); sum += __shfl_xor(sum, 8);
      const float mu = sum * (1.f / 64.f);
      float vs = 0.f;
#pragma unroll
      for (int nt = 0; nt < 4; ++nt) {
        const float d = acc[mt][nt][rr] - mu;
        vs += d * d;
      }
      vs += __shfl_xor(vs, 1); vs += __shfl_xor(vs, 2);
      vs += __shfl_xor(vs, 4); vs += __shfl_xor(vs, 8);
      const float rs = rsqrtf(vs * (1.f / 64.f) + EPS);
      float xn[4];
#pragma unroll
      for (int nt = 0; nt < 4; ++nt)
        xn[nt] = (acc[mt][nt][rr] - mu) * rs * gam[nt] + bet[nt];
      const float2 t0 = tab[s * 32 + l15];
      const float2 t1 = tab[s * 32 + 16 + l15];
      float ro[4];
      ro[0] = xn[0] * t0.x - xn[2] * t0.y;
      ro[2] = xn[2] * t0.x + xn[0] * t0.y;
      ro[1] = xn[1] * t1.x - xn[3] * t1.y;
      ro[3] = xn[3] * t1.x + xn[1] * t1.y;
      unsigned short* row = plane + (((size_t)(b * NH + h) * SEQ + s) * HD);
#pragma unroll
      for (int nt = 0; nt < 4; ++nt)
        row[nt * 16 + l15] = f2bf(ro[nt] * scale);
    }
}

// ---------------------------------------------------------------------------
// Flash attention: round-12 structure; softmax SHIFT removed (scale-invariant:
// |s_log2| <= 11.6 -> p = exp2(s) in [3e-4, 3.1e3], fp32/bf16-safe, the l
// normalization cancels the scale exactly). Packing via single v_perm.
// ---------------------------------------------------------------------------
#define KIDX(g,k0,key,dim) (((((g)*2+(k0))*64+(key))*32)+(dim))
#define VOFF 8192
#define POFF 16384
#define PIDX(w,row,col) (POFF + ((w)*32+(row))*72 + (col))

__global__ __launch_bounds__(512, 4)
void attn_mfma6(const unsigned short* __restrict__ Qb, const unsigned short* __restrict__ Kb,
                const unsigned short* __restrict__ VbT, unsigned short* __restrict__ O) {
  __shared__ __attribute__((aligned(16))) unsigned short SMEM[34816];  // 68 KB

  const int tid  = threadIdx.x;
  const int wv   = tid >> 6;
  const int g    = wv >> 2;
  const int qsub = wv & 3;
  const int lane = tid & 63;
  const int l15  = lane & 15;
  const int quad = lane >> 4;
  const int bh = blockIdx.y;
  const int q0 = blockIdx.x * 128;
  const size_t base  = (size_t)bh * (SEQ * HD);
  const size_t baseT = (size_t)bh * (HD * SEQ);
  const int qsw = (quad ^ ((l15 >> 1) & 3)) * 8;

  bf16x8 qf[2][2];
#pragma unroll
  for (int mt = 0; mt < 2; ++mt)
#pragma unroll
    for (int k0 = 0; k0 < 2; ++k0)
      qf[mt][k0] = *(const bf16x8*)&Qb[base + (size_t)(q0 + qsub * 32 + mt * 16 + l15) * HD + k0 * 32 + quad * 8];

  bf16x8 ones;
#pragma unroll
  for (int j = 0; j < 8; ++j) ones[j] = (short)0x3F80;

  f32x4 oaccT[4][2];
  f32x4 ol[2];
#pragma unroll
  for (int nb = 0; nb < 4; ++nb)
#pragma unroll
    for (int mt = 0; mt < 2; ++mt) oaccT[nb][mt] = (f32x4){0.f, 0.f, 0.f, 0.f};
  ol[0] = (f32x4){0.f, 0.f, 0.f, 0.f};
  ol[1] = (f32x4){0.f, 0.f, 0.f, 0.f};

  const int sseg = (((lane & 3) ^ ((lane >> 3) & 3))) * 8;
  const unsigned short* srcK = Kb + base + (size_t)(qsub * 16 + (lane >> 2)) * HD + sseg;
  const unsigned short* srcV = VbT + baseT + (size_t)(qsub * 16 + (lane >> 2)) * SEQ + sseg;
  unsigned short* dstK0 = &SMEM[KIDX(g, 0, qsub * 16, 0)];
  unsigned short* dstK1 = &SMEM[KIDX(g, 1, qsub * 16, 0)];
  unsigned short* dstV0 = &SMEM[VOFF + KIDX(g, 0, qsub * 16, 0)];
  unsigned short* dstV1 = &SMEM[VOFF + KIDX(g, 1, qsub * 16, 0)];

  for (int it = 0; it < SEQ / 128; ++it) {
    const int kt = it * 128 + g * 64;
    __syncthreads();
    async_copy16(srcK + (size_t)kt * HD,      dstK0);
    async_copy16(srcK + (size_t)kt * HD + 32, dstK1);
    async_copy16(srcV + kt,                   dstV0);
    async_copy16(srcV + kt + 32,              dstV1);
    __syncthreads();

    f32x4 st[4][2];
#pragma unroll
    for (int nb = 0; nb < 4; ++nb)
#pragma unroll
      for (int mt = 0; mt < 2; ++mt) st[nb][mt] = (f32x4){0.f, 0.f, 0.f, 0.f};
#pragma unroll
    for (int k0 = 0; k0 < 2; ++k0)
#pragma unroll
      for (int nb = 0; nb < 4; ++nb) {
        bf16x8 kf = *(const bf16x8*)&SMEM[KIDX(g, k0, nb * 16 + l15, qsw)];
#pragma unroll
        for (int mt = 0; mt < 2; ++mt)
          st[nb][mt] = __builtin_amdgcn_mfma_f32_16x16x32_bf16(kf, qf[mt][k0], st[nb][mt], 0, 0, 0);
      }

    // softmax numerator: p = exp2(s), no shift (scale cancels in 1/l)
#pragma unroll
    for (int mt = 0; mt < 2; ++mt)
#pragma unroll
      for (int nb = 0; nb < 4; ++nb) {
        const float p0 = EXP2F(st[nb][mt][0]);
        const float p1 = EXP2F(st[nb][mt][1]);
        const float p2 = EXP2F(st[nb][mt][2]);
        const float p3 = EXP2F(st[nb][mt][3]);
        uint2 pk;
        pk.x = pack_bf16_trunc(p0, p1);
        pk.y = pack_bf16_trunc(p2, p3);
        *(uint2*)&SMEM[PIDX(wv, mt * 16 + l15, nb * 16 + quad * 4)] = pk;
      }

#pragma unroll
    for (int k0 = 0; k0 < 2; ++k0) {
      bf16x8 pf0 = *(const bf16x8*)&SMEM[PIDX(wv, 0 * 16 + l15, k0 * 32 + quad * 8)];
      bf16x8 pf1 = *(const bf16x8*)&SMEM[PIDX(wv, 1 * 16 + l15, k0 * 32 + quad * 8)];
      ol[0] = __builtin_amdgcn_mfma_f32_16x16x32_bf16(ones, pf0, ol[0], 0, 0, 0);
      ol[1] = __builtin_amdgcn_mfma_f32_16x16x32_bf16(ones, pf1, ol[1], 0, 0, 0);
#pragma unroll
      for (int nb = 0; nb < 4; ++nb) {
        bf16x8 vf = *(const bf16x8*)&SMEM[VOFF + KIDX(g, k0, nb * 16 + l15, qsw)];
        oaccT[nb][0] = __builtin_amdgcn_mfma_f32_16x16x32_bf16(vf, pf0, oaccT[nb][0], 0, 0, 0);
        oaccT[nb][1] = __builtin_amdgcn_mfma_f32_16x16x32_bf16(vf, pf1, oaccT[nb][1], 0, 0, 0);
      }
    }
  }

  __syncthreads();
  f32x4* MO = (f32x4*)SMEM;
  float* ML = (float*)(SMEM + POFF);
  if (g == 1) {
#pragma unroll
    for (int mt = 0; mt < 2; ++mt) {
#pragma unroll
      for (int nb = 0; nb < 4; ++nb)
        MO[(((qsub * 2 + mt) * 4 + nb) << 6) + lane] = oaccT[nb][mt];
      if (quad == 0)
        ML[(qsub * 2 + mt) * 16 + l15] = ol[mt][0];
    }
  }
  __syncthreads();
  if (g == 0) {
    const int b = bh >> 4, h = bh & 15;
#pragma unroll
    for (int mt = 0; mt < 2; ++mt) {
      const float l1 = ML[(qsub * 2 + mt) * 16 + l15];
      const float inv = 1.f / (ol[mt][0] + l1);
      const int qrow = q0 + qsub * 32 + mt * 16 + l15;
      unsigned short* orow = O + ((size_t)(b * SEQ + qrow)) * DIM + h * HD;
#pragma unroll
      for (int nb = 0; nb < 4; ++nb) {
        f32x4 o1 = MO[(((qsub * 2 + mt) * 4 + nb) << 6) + lane];
        uint2 pk;
        pk.x = ((unsigned int)f2bf((oaccT[nb][mt][1] + o1[1]) * inv) << 16) |
               f2bf((oaccT[nb][mt][0] + o1[0]) * inv);
        pk.y = ((unsigned int)f2bf((oaccT[nb][mt][3] + o1[3]) * inv) << 16) |
               f2bf((oaccT[nb][mt][2] + o1[2]) * inv);
        *(uint2*)&orow[nb * 16 + quad * 4] = pk;
      }
    }
  }
}

// ---------------------------------------------------------------------------
// Output projection: 64x64 tile, 256 thr = 4 waves (wave = 32x32), dbuf +
// swizzled staging, grid 1024 = 4 blocks/CU -> 16 waves/CU (2x round-12).
// ---------------------------------------------------------------------------
__global__ __launch_bounds__(256)
void gemm_out(const unsigned short* __restrict__ A, const unsigned short* __restrict__ B,
              const void* __restrict__ biasv, void* __restrict__ Cv,
              int M, int N, int K, const int* __restrict__ flagp) {
  __shared__ __attribute__((aligned(16))) unsigned short As[2][64 * 32];  // 8 KB
  __shared__ __attribute__((aligned(16))) unsigned short Bs[2][64 * 32];  // 8 KB

  const int tid  = threadIdx.x;
  const int wv   = tid >> 6;
  const int lane = tid & 63;
  const int l15  = lane & 15;
  const int quad = lane >> 4;
  const int wm = wv & 1, wn = wv >> 1;   // 2x2 wave grid of 32x32 tiles
  const int bm = blockIdx.y * 64;
  const int bn = blockIdx.x * 64;
  const int qsw = (quad ^ ((l15 >> 1) & 3)) * 8;

  f32x4 acc[2][2];
#pragma unroll
  for (int i = 0; i < 2; ++i)
#pragma unroll
    for (int j = 0; j < 2; ++j) acc[i][j] = (f32x4){0.f, 0.f, 0.f, 0.f};

  const int srow = tid >> 2;                              // 0..63
  const int kseg = (((tid & 3) ^ ((tid >> 3) & 3))) * 8;  // swizzled DMA src
  const unsigned short* Ag = A + (size_t)(bm + srow) * K + kseg;
  const unsigned short* Bg = B + (size_t)(bn + srow) * K + kseg;

  async_copy16(Ag, &As[0][wv * 512]);
  async_copy16(Bg, &Bs[0][wv * 512]);
  __syncthreads();

  for (int k0 = 0; k0 < K; k0 += 32) {
    const int cur = (k0 >> 5) & 1, nxt = cur ^ 1;
    if (k0 + 32 < K) {
      async_copy16(Ag + k0 + 32, &As[nxt][wv * 512]);
      async_copy16(Bg + k0 + 32, &Bs[nxt][wv * 512]);
    }

    bf16x8 af[2], bf[2];
#pragma unroll
    for (int mt = 0; mt < 2; ++mt)
      af[mt] = *(const bf16x8*)&As[cur][(wm * 32 + mt * 16 + l15) * 32 + qsw];
#pragma unroll
    for (int nt = 0; nt < 2; ++nt)
      bf[nt] = *(const bf16x8*)&Bs[cur][(wn * 32 + nt * 16 + l15) * 32 + qsw];
#pragma unroll
    for (int mt = 0; mt < 2; ++mt)
#pragma unroll
      for (int nt = 0; nt < 2; ++nt)
        acc[mt][nt] = __builtin_amdgcn_mfma_f32_16x16x32_bf16(af[mt], bf[nt], acc[mt][nt], 0, 0, 0);
    __syncthreads();
  }

  const bool isf32 = (*flagp != 0);
#pragma unroll
  for (int mt = 0; mt < 2; ++mt)
#pragma unroll
    for (int rr = 0; rr < 4; ++rr) {
      const int r = bm + wm * 32 + mt * 16 + quad * 4 + rr;
#pragma unroll
      for (int nt = 0; nt < 2; ++nt) {
        const int c = bn + wn * 32 + nt * 16 + l15;
        const float bias_c = isf32 ? ((const float*)biasv)[c]
                                   : bf2f(((const unsigned short*)biasv)[c]);
        const float o = acc[mt][nt][rr] + bias_c;
        if (isf32) ((float*)Cv)[(size_t)r * N + c] = o;
        else       ((unsigned short*)Cv)[(size_t)r * N + c] = f2bf(o);
      }
    }
}

// ---------------------------------------------------------------------------
extern "C" void kernel_launch(void* const* d_in, const int* in_sizes, int n_in,
                              void* d_out, int out_size, void* d_ws, size_t ws_size,
                              hipStream_t stream) {
  const void* x      = d_in[0];
  const void* w_qkv  = d_in[1];
  const void* w_proj = d_in[2];
  const void* b_proj = d_in[3];
  const void* q_g    = d_in[4];
  const void* q_b    = d_in[5];
  const void* k_g    = d_in[6];
  const void* k_b    = d_in[7];

  const size_t PLANE = (size_t)BATCH * NH * SEQ * HD;

  unsigned short* Qb  = (unsigned short*)d_ws;
  unsigned short* Kb  = Qb + PLANE;
  unsigned short* VbT = Kb + PLANE;
  unsigned short* xb  = VbT + PLANE;             // xb, later attnout
  unsigned short* wqb = xb + PLANE;
  unsigned short* wpb = wqb + NWQ;
  float2* tab = (float2*)(wpb + NWP);
  int* flag = (int*)(tab + SEQ * 32);

  // 1) fused detect + table + convert (one dispatch)
  hipLaunchKernelGGL(prep, dim3(NCONVBLK + NTABBLK), dim3(256), 0, stream,
                     x, w_qkv, w_proj, xb, wqb, wpb, tab, flag);

  // 2) QKV projection + fused LN/RoPE -> bf16 Q/K/V^T planes
  {
    dim3 grid((3 * DIM) / 128, (BATCH * SEQ) / 128);
    hipLaunchKernelGGL(gemm_qkv, grid, dim3(512), 0, stream,
                       xb, wqb, Qb, Kb, VbT, q_g, q_b, k_g, k_b, tab, flag);
  }
  // 3) flash attention -> bf16 attnout (xb slot)
  {
    dim3 grid(SEQ / 128, BATCH * NH);
    hipLaunchKernelGGL(attn_mfma6, grid, dim3(512), 0, stream,
                       Qb, Kb, VbT, xb);
  }
  // 4) output projection + bias -> d_out (flag dtype)
  {
    dim3 grid(DIM / 64, (BATCH * SEQ) / 64);
    hipLaunchKernelGGL(gemm_out, grid, dim3(256), 0, stream,
                       xb, wpb, b_proj, d_out, BATCH * SEQ, DIM, DIM, flag);
  }
}